// Round 8
// baseline (161.870 us; speedup 1.0000x reference)
//
#include <hip/hip_runtime.h>
#include <hip/hip_bf16.h>
#include <math.h>
#include <stdint.h>

#define B_N   512
#define D_N   768
#define R_N   128
#define C_NEW 10
#define C_OLD 100
#define C_TOT 110
#define MARGIN_F    5.0f
#define VAR_FLOOR_F 1e-4f
#define BIG_F       1e6f

typedef __bf16 bf16;
typedef __bf16 bf16x4 __attribute__((ext_vector_type(4)));
typedef __bf16 bf16x8 __attribute__((ext_vector_type(8)));
typedef float  f32x4  __attribute__((ext_vector_type(4)));

__device__ __forceinline__ float cleanf(float v) { return isfinite(v) ? v : 0.0f; }

// order-preserving float->uint encode (monotone, handles negatives)
__device__ __forceinline__ unsigned encf(float f) {
    unsigned u = __float_as_uint(f);
    return (u & 0x80000000u) ? ~u : (u | 0x80000000u);
}
__device__ __forceinline__ float decf(unsigned u) {
    return (u & 0x80000000u) ? __uint_as_float(u & 0x7fffffffu) : __uint_as_float(~u);
}

// global->LDS direct DMA, 16B per lane; LDS dst is wave-uniform base + lane*16
#define GL16(gp, lp)                                                            \
    __builtin_amdgcn_global_load_lds(                                           \
        (const __attribute__((address_space(1))) unsigned int*)(gp),            \
        (__attribute__((address_space(3))) unsigned int*)(lp), 16, 0, 0)

// Swizzled element offset within a row of 768: granule g (8 elems) of each
// 64-elem chunk is stored at g ^ (row & 7). Applied at WRITE time in prep;
// read side (MFMA frags / zdot) applies the same XOR. LDS stays linear so
// global_load_lds works (both-sides-or-neither rule).
__device__ __forceinline__ int swz_elem(int D, int row) {
    int k0 = D & ~63;
    int g  = (D >> 3) & 7;
    return k0 + (((g ^ (row & 7))) << 3) + (D & 7);
}

// ---------------------------------------------------------------------------
// prep_fused: grid 238 x 256.
//  [0,128):   z-blocks — clean z -> swizzled bf16 zbf + znorm[b]; blk 0 inits ominE.
//  [128,238): gram+transpose blocks — per class c, one K-loop over the f32
//             bases (read ONCE) that simultaneously produces:
//               G[c] = B_c^T B_c (bf16, MFMA),
//               basesT[c][r][d] swizzled bf16 (written per-chunk from LDS),
//               m_c[c][r] = sum_d mu_d B[d][r] (strip-dot, shares LDS reads
//               with the transpose write), munorm[c].
//             R7 ran separate transpose blocks -> 84 MB of f32 reads; this
//             halves prep HBM fetch and drops 660 blocks.
// ---------------------------------------------------------------------------
__global__ __launch_bounds__(256, 2)
void prep_fused(const float* __restrict__ z,
                const float* __restrict__ cur_means, const float* __restrict__ old_means,
                const float* __restrict__ cur_bases, const float* __restrict__ old_bases,
                bf16* __restrict__ zbf, float* __restrict__ znorm,
                float* __restrict__ munorm, float* __restrict__ m_c,
                bf16* __restrict__ basesT, bf16* __restrict__ G,
                unsigned* __restrict__ ominE)
{
    const int bid = blockIdx.x, t = threadIdx.x;
    __shared__ __align__(16) unsigned char lds[18432 + 256 + 1024];
    const int wave = t >> 6, lane = t & 63;

    if (bid < 128) {
        // ---------------- z path ----------------
        if (bid == 0) {
            ominE[t] = 0xFFFFFFFFu;
            ominE[256 + t] = 0xFFFFFFFFu;
        }
        const int b = bid * 4 + wave;
        const float4* src = (const float4*)(z + (size_t)b * D_N);
        bf16* dst = zbf + (size_t)b * D_N;
        float nrm = 0.f;
        #pragma unroll
        for (int i = 0; i < 3; ++i) {
            const int D = (lane + i * 64) * 4;      // element index in row
            float4 v = src[lane + i * 64];
            v.x = cleanf(v.x); v.y = cleanf(v.y); v.z = cleanf(v.z); v.w = cleanf(v.w);
            nrm += v.x * v.x + v.y * v.y + v.z * v.z + v.w * v.w;
            bf16x4 w;
            w[0] = (bf16)v.x; w[1] = (bf16)v.y; w[2] = (bf16)v.z; w[3] = (bf16)v.w;
            *(bf16x4*)(dst + swz_elem(D, b)) = w;
        }
        #pragma unroll
        for (int off = 32; off >= 1; off >>= 1) nrm += __shfl_xor(nrm, off, 64);
        if (lane == 0) znorm[b] = nrm;
        return;
    }

    // ---------------- gram + transpose + m_c + munorm path ----------------
    const int c = bid - 128;
    const float* Bc = (c < C_NEW) ? cur_bases + (size_t)c * D_N * R_N
                                  : old_bases + (size_t)(c - C_NEW) * D_N * R_N;
    const float* mu = (c < C_NEW) ? cur_means + (size_t)c * D_N
                                  : old_means + (size_t)(c - C_NEW) * D_N;
    bf16*  sT   = (bf16*)lds;                     // [128][72] padded
    float* sMuF = (float*)(lds + 18432);          // 64 f32
    float* sRed = (float*)(lds + 18432 + 256);    // 256 f32
    const int quad = lane >> 4, l15 = lane & 15;
    const int wrg = (wave >> 1) * 64, wsg = (wave & 1) * 64;
    const int rg = t & 31, dgq = t >> 5;          // r-quad / d-quad-group

    f32x4 acc[4][4];
    #pragma unroll
    for (int i = 0; i < 4; ++i)
        #pragma unroll
        for (int j = 0; j < 4; ++j) acc[i][j] = (f32x4)0.0f;
    float mAcc = 0.f, muN = 0.f;

    float4 pf[8];
    #pragma unroll
    for (int i = 0; i < 2; ++i) {
        const int dg = i * 8 + dgq;
        const float* src = Bc + (size_t)(dg * 4) * R_N + rg * 4;
        #pragma unroll
        for (int m = 0; m < 4; ++m) pf[i * 4 + m] = *(const float4*)(src + m * R_N);
    }

    for (int kc = 0; kc < 12; ++kc) {
        const int k0 = kc * 64;
        __syncthreads();
        #pragma unroll
        for (int i = 0; i < 2; ++i) {
            const int dg = i * 8 + dgq;
            #pragma unroll
            for (int j = 0; j < 4; ++j) {
                const int R = rg * 4 + j;
                bf16x4 w;
                w[0] = (bf16)pf[i * 4 + 0][j];
                w[1] = (bf16)pf[i * 4 + 1][j];
                w[2] = (bf16)pf[i * 4 + 2][j];
                w[3] = (bf16)pf[i * 4 + 3][j];
                *(bf16x4*)(sT + R * 72 + dg * 4) = w;
            }
        }
        if (t < 64) {
            float mv = mu[k0 + t];
            sMuF[t] = mv;
            muN += mv * mv;
        }
        if (kc < 11) {
            #pragma unroll
            for (int i = 0; i < 2; ++i) {
                const int dg = i * 8 + dgq;
                const float* src = Bc + (size_t)((kc + 1) * 64 + dg * 4) * R_N + rg * 4;
                #pragma unroll
                for (int m = 0; m < 4; ++m) pf[i * 4 + m] = *(const float4*)(src + m * R_N);
            }
        }
        __syncthreads();
        #pragma unroll
        for (int kk = 0; kk < 64; kk += 32) {
            bf16x8 af[4], bg[4];
            #pragma unroll
            for (int i = 0; i < 4; ++i) af[i] = *(const bf16x8*)(sT + (wrg + 16 * i + l15) * 72 + kk + quad * 8);
            #pragma unroll
            for (int j = 0; j < 4; ++j) bg[j] = *(const bf16x8*)(sT + (wsg + 16 * j + l15) * 72 + kk + quad * 8);
            #pragma unroll
            for (int i = 0; i < 4; ++i)
                #pragma unroll
                for (int j = 0; j < 4; ++j)
                    acc[i][j] = __builtin_amdgcn_mfma_f32_16x16x32_bf16(af[i], bg[j], acc[i][j], 0, 0, 0);
        }
        // m_c strip-dot + swizzled basesT chunk write (shares the LDS reads):
        // row rr = t>>1, half hf = t&1 covers granules g = hf*4..hf*4+3.
        {
            const int rr = t >> 1, hf = t & 1;
            const float* mf = sMuF + hf * 32;
            bf16* dstRow = basesT + (size_t)c * R_N * D_N + (size_t)rr * D_N + k0;
            #pragma unroll
            for (int m = 0; m < 4; ++m) {
                const int g = hf * 4 + m;
                bf16x8 v = *(const bf16x8*)(sT + rr * 72 + g * 8);
                #pragma unroll
                for (int e = 0; e < 8; ++e) mAcc += (float)v[e] * mf[m * 8 + e];
                *(bf16x8*)(dstRow + ((g ^ (rr & 7)) << 3)) = v;
            }
        }
    }
    #pragma unroll
    for (int i = 0; i < 4; ++i)
        #pragma unroll
        for (int j = 0; j < 4; ++j)
            #pragma unroll
            for (int reg = 0; reg < 4; ++reg) {
                int r = wrg + 16 * i + quad * 4 + reg;
                int s = wsg + 16 * j + l15;
                G[(size_t)c * 16384 + (size_t)r * 128 + s] = (bf16)acc[i][j][reg];
            }
    sRed[t] = mAcc;
    __syncthreads();
    if (t < 128) m_c[c * R_N + t] = sRed[2 * t] + sRed[2 * t + 1];
    if (t < 64) {
        #pragma unroll
        for (int off = 32; off >= 1; off >>= 1) muN += __shfl_xor(muN, off, 64);
        if (lane == 0) munorm[c] = muN;
    }
}

// ---------------------------------------------------------------------------
// main_dist: grid 896 x 256, 4 blocks/CU. Decode: c = (fid&7) + 8*((fid%112)>>3),
// mt = fid/112 -> 8 mt-blocks of a class share one XCD's L2 (basesT/G reuse).
// K-loop (12 chunks): LDS staging via global_load_lds width-16 DMA from the
// PRE-SWIZZLED zbf/basesT (linear LDS dest, XOR applied at frag-read time).
// acc1 = z x B; epilogue: coeff = acc1 - m_c -> sC; par/cn; GEMM2 H = coeff x G
// (G straight from L2); qsum; dist with nd2 = znorm - 2 zdot + munorm.
// ---------------------------------------------------------------------------
#define PADC 136
#define SM_A    0                       // 64 x 64 bf16 linear = 8192
#define SM_B    8192                    // 128 x 64 bf16 linear = 16384 -> 24576
#define SM_C    0                       // 64x136 bf16 = 17408 (overlay sA/sB)
#define SM_MU   24576                   // 768 bf16 = 1536 -> 26112
#define SM_M    26112                   // 128 f32 = 512 -> 26624
#define SM_INV  26624                   // 512 -> 27136
#define SM_Q    27136                   // 256 -> 27392
#define SM_PAR  27392                   // 256 -> 27648
#define SM_CN   27648                   // 256 -> 27904
#define SM_ZD   27904                   // 256 -> 28160
#define SM_T2   28160                   // 2048 -> 30208
#define SM_SZ   30208                   // 4+ blocks/CU

__global__ __launch_bounds__(256, 4)
void main_dist(const bf16* __restrict__ zbf, const bf16* __restrict__ basesT,
               const bf16* __restrict__ G, const float* __restrict__ m_c,
               const float* __restrict__ cur_vars, const float* __restrict__ old_vars,
               const float* __restrict__ cur_means, const float* __restrict__ old_means,
               const float* __restrict__ znorm, const float* __restrict__ munorm,
               float* __restrict__ gdist, unsigned* __restrict__ ominE)
{
    const int fid = blockIdx.x;
    const int x = fid & 7;
    const int y = (fid % 112) >> 3;
    const int mt = fid / 112;
    const int c = x + 8 * y;
    if (c >= C_TOT) return;

    __shared__ __align__(16) unsigned char smem[SM_SZ];
    unsigned char* sAb = smem + SM_A;
    unsigned char* sBb = smem + SM_B;
    bf16*  sC   = (bf16*)(smem + SM_C);
    bf16*  sMuB = (bf16*)(smem + SM_MU);
    float* sM   = (float*)(smem + SM_M);
    float* sInv = (float*)(smem + SM_INV);
    float* sQ   = (float*)(smem + SM_Q);
    float* sPar = (float*)(smem + SM_PAR);
    float* sCn  = (float*)(smem + SM_CN);
    float* sZd  = (float*)(smem + SM_ZD);
    float* sT2  = (float*)(smem + SM_T2);

    const int tid = threadIdx.x, wave = tid >> 6, lane = tid & 63;
    const int quad = lane >> 4, l15 = lane & 15;
    const int wr  = (wave >> 1) * 32;      // row half of 64
    const int wcc = (wave & 1) * 64;       // col half of 128

    const int b0 = mt * 64;
    const float* vars = (c < C_NEW) ? cur_vars + (size_t)c * (R_N + 1)
                                    : old_vars + (size_t)(c - C_NEW) * (R_N + 1);
    const float* mu = (c < C_NEW) ? cur_means + (size_t)c * D_N
                                  : old_means + (size_t)(c - C_NEW) * D_N;

    if (tid < 128) {
        sM[tid]   = m_c[c * R_N + tid];
        sInv[tid] = 1.0f / fmaxf(vars[tid], VAR_FLOOR_F);
    }
    if (tid < 64) sQ[tid] = 0.0f;
    for (int i = tid; i < D_N; i += 256) sMuB[i] = (bf16)mu[i];

    f32x4 acc1[2][4];
    #pragma unroll
    for (int i = 0; i < 2; ++i)
        #pragma unroll
        for (int j = 0; j < 4; ++j) acc1[i][j] = (f32x4)0.0f;
    float zd = 0.f;
    const int zrow = tid >> 2, zpart = tid & 3;   // 4 threads per batch row

    // per-thread DMA source offset: row = wave*8 + (lane>>3) (+32 per extra call),
    // 16B granule (lane&7) within the 128B chunk-row
    const char* BbB = (const char*)basesT + (size_t)c * (R_N * D_N * 2);
    const char* AzB = (const char*)zbf + (size_t)b0 * (D_N * 2);
    const int offRC = (wave * 8 + (lane >> 3)) * (D_N * 2) + (lane & 7) * 16;
    char* ldsB = (char*)sBb + wave * 1024;
    char* ldsA = (char*)sAb + wave * 1024;

    for (int kc = 0; kc < 12; ++kc) {
        const int kb = kc * 128;               // byte offset within a 1536B row
        const int k0 = kc * 64;                // element offset
        __syncthreads();                       // previous chunk's readers done
        #pragma unroll
        for (int p = 0; p < 4; ++p)
            GL16(BbB + offRC + p * (32 * D_N * 2) + kb, ldsB + p * 4096);
        #pragma unroll
        for (int q = 0; q < 2; ++q)
            GL16(AzB + offRC + q * (32 * D_N * 2) + kb, ldsA + q * 4096);
        __syncthreads();                       // vmcnt(0) drain inserted by compiler
        #pragma unroll
        for (int kk = 0; kk < 64; kk += 32) {
            const int gbase = kk >> 3;
            bf16x8 af[2], bg[4];
            #pragma unroll
            for (int i = 0; i < 2; ++i) {
                const int rowA = wr + 16 * i + l15;
                af[i] = *(const bf16x8*)(sAb + rowA * 128 + (((gbase + quad) ^ (rowA & 7)) << 4));
            }
            #pragma unroll
            for (int j = 0; j < 4; ++j) {
                const int rowB = wcc + 16 * j + l15;
                bg[j] = *(const bf16x8*)(sBb + rowB * 128 + (((gbase + quad) ^ (rowB & 7)) << 4));
            }
            #pragma unroll
            for (int i = 0; i < 2; ++i)
                #pragma unroll
                for (int j = 0; j < 4; ++j)
                    acc1[i][j] = __builtin_amdgcn_mfma_f32_16x16x32_bf16(af[i], bg[j], acc1[i][j], 0, 0, 0);
        }
        // zdot co-issue: z[row] . mu over this chunk (2 granules per thread)
        #pragma unroll
        for (int gg = 0; gg < 2; ++gg) {
            const int g = zpart * 2 + gg;
            bf16x8 a = *(const bf16x8*)(sAb + zrow * 128 + ((g ^ (zrow & 7)) << 4));
            bf16x8 b = *(const bf16x8*)(sMuB + k0 + g * 8);
            #pragma unroll
            for (int e = 0; e < 8; ++e) zd += (float)a[e] * (float)b[e];
        }
    }

    // zdot reduce: 4 consecutive lanes share a row
    zd += __shfl_xor(zd, 1, 64);
    zd += __shfl_xor(zd, 2, 64);
    if ((tid & 3) == 0) sZd[zrow] = zd;
    __syncthreads();   // all waves done reading sA/sB; sZd complete

    // coeff = acc1 - m_c -> sC (overlays sA/sB region)
    #pragma unroll
    for (int j = 0; j < 4; ++j) {
        float mcv = sM[wcc + 16 * j + l15];
        #pragma unroll
        for (int i = 0; i < 2; ++i)
            #pragma unroll
            for (int reg = 0; reg < 4; ++reg)
                sC[(wr + 16 * i + quad * 4 + reg) * PADC + wcc + 16 * j + l15] =
                    (bf16)(acc1[i][j][reg] - mcv);
    }
    __syncthreads();

    // par / cnorm per row (64 rows, 4 threads/row over 32 cols each)
    {
        int row = tid >> 2, qtr = tid & 3;
        float par = 0.f, cn = 0.f;
        #pragma unroll
        for (int m = 0; m < 4; ++m) {
            bf16x8 v = *(const bf16x8*)(sC + row * PADC + qtr * 32 + m * 8);
            #pragma unroll
            for (int e = 0; e < 8; ++e) {
                float f = (float)v[e];
                int col = qtr * 32 + m * 8 + e;
                cn  += f * f;
                par += f * f * sInv[col];
            }
        }
        sT2[tid] = par;
        sT2[256 + tid] = cn;
    }
    __syncthreads();
    if (tid < 64) {
        sPar[tid] = sT2[tid * 4] + sT2[tid * 4 + 1] + sT2[tid * 4 + 2] + sT2[tid * 4 + 3];
        sCn[tid]  = sT2[256 + tid * 4] + sT2[256 + tid * 4 + 1]
                  + sT2[256 + tid * 4 + 2] + sT2[256 + tid * 4 + 3];
    }

    // GEMM2: H = coeff x G; G-fragments straight from global (L2-hot)
    const bf16* Gc = G + (size_t)c * 16384;
    f32x4 acc2[2][4];
    #pragma unroll
    for (int i = 0; i < 2; ++i)
        #pragma unroll
        for (int j = 0; j < 4; ++j) acc2[i][j] = (f32x4)0.0f;
    #pragma unroll
    for (int kc4 = 0; kc4 < 4; ++kc4) {
        const int kb = kc4 * 32;
        bf16x8 af[2], bg[4];
        #pragma unroll
        for (int i = 0; i < 2; ++i) af[i] = *(const bf16x8*)(sC + (wr + 16 * i + l15) * PADC + kb + quad * 8);
        #pragma unroll
        for (int j = 0; j < 4; ++j) bg[j] = *(const bf16x8*)(Gc + (size_t)(wcc + 16 * j + l15) * 128 + kb + quad * 8);
        #pragma unroll
        for (int i = 0; i < 2; ++i)
            #pragma unroll
            for (int j = 0; j < 4; ++j)
                acc2[i][j] = __builtin_amdgcn_mfma_f32_16x16x32_bf16(af[i], bg[j], acc2[i][j], 0, 0, 0);
    }

    // qsum[row] = sum_s H[row][s] * coeff[row][s]  (coeff from sC)
    #pragma unroll
    for (int i = 0; i < 2; ++i)
        #pragma unroll
        for (int reg = 0; reg < 4; ++reg) {
            const int row = wr + 16 * i + quad * 4 + reg;
            float qp = 0.f;
            #pragma unroll
            for (int j = 0; j < 4; ++j)
                qp += acc2[i][j][reg] * (float)sC[row * PADC + wcc + 16 * j + l15];
            qp += __shfl_xor(qp, 1, 64);
            qp += __shfl_xor(qp, 2, 64);
            qp += __shfl_xor(qp, 4, 64);
            qp += __shfl_xor(qp, 8, 64);
            if (l15 == 0) atomicAdd(&sQ[row], qp);
        }
    __syncthreads();

    // final dist per row
    if (tid < 64) {
        int b = b0 + tid;
        float nd2 = znorm[b] - 2.0f * sZd[tid] + munorm[c];
        float res = fmaxf(vars[R_N], VAR_FLOOR_F);
        float dist = (sPar[tid] + (nd2 - 2.0f * sCn[tid] + sQ[tid]) / res) / (float)D_N;
        if (!isfinite(dist)) dist = BIG_F;
        if (c < C_NEW) {
            gdist[(size_t)b * C_NEW + c] = dist;
        } else {
            atomicMin(ominE + b, encf(dist));
        }
    }
}

// ---------------------------------------------------------------------------
// finalize: single block, 512 threads (one per batch row).
// ---------------------------------------------------------------------------
__global__ __launch_bounds__(512)
void finalize(const float* __restrict__ gdist, const unsigned* __restrict__ ominE,
              const int* __restrict__ labels, const int* __restrict__ ncid,
              float* __restrict__ out)
{
    __shared__ float acc[C_NEW * 4];
    __shared__ int sNcid[C_NEW];
    const int t = threadIdx.x;
    if (t < C_NEW * 4) acc[t] = 0.f;
    if (t < C_NEW) sNcid[t] = ncid[t];
    __syncthreads();

    {
        float mn = decf(ominE[t]);
        const int lab = labels[t];
        #pragma unroll
        for (int k = 0; k < C_NEW; ++k) {
            if (lab == sNcid[k]) {
                int col = min(max(sNcid[k], 0), C_NEW - 1);
                float ow = gdist[(size_t)t * C_NEW + col];
                atomicAdd(&acc[k * 4 + 0], 1.0f);
                atomicAdd(&acc[k * 4 + 1], fmaxf(0.0f, MARGIN_F + ow - mn));
                atomicAdd(&acc[k * 4 + 2], ow);
                atomicAdd(&acc[k * 4 + 3], mn);
            }
        }
    }
    __syncthreads();

    if (t == 0) {
        float total = 0.f, own = 0.f, old = 0.f, nv = 0.f;
        #pragma unroll
        for (int k = 0; k < C_NEW; ++k) {
            float cnt = acc[k * 4 + 0];
            float den = fmaxf(cnt, 1.0f);
            if (cnt > 0.f) {
                nv += 1.f;
                total += acc[k * 4 + 1] / den;
                own   += acc[k * 4 + 2] / den;
                old   += acc[k * 4 + 3] / den;
            }
        }
        float nvd = fmaxf(nv, 1.0f);
        out[0] = total / nvd;
        out[1] = own / nvd;
        out[2] = old / nvd;
    }
}

// ---------------------------------------------------------------------------
// workspace layout (bytes):
//   gdist  @ 0        : 20480    (512 x 10 f32, new classes only)
//   ominE  @ 20480    : 2048     (512 encoded old-min; init by prep blk 0)
//   zbf    @ 22528    : 786432   (swizzled bf16 z)
//   znorm  @ 808960   : 2048
//   munorm @ 811008   : 512
//   m_c    @ 811520   : 56320
//   basesT @ 867840   : 21626880 (swizzled; written by gram blocks)
//   G      @ 22494720 : 3604480  -> total ~26.1 MB
// ---------------------------------------------------------------------------
extern "C" void kernel_launch(void* const* d_in, const int* in_sizes, int n_in,
                              void* d_out, int out_size, void* d_ws, size_t ws_size,
                              hipStream_t stream)
{
    const float* features  = (const float*)d_in[0];
    const int*   labels    = (const int*)d_in[1];
    const int*   ncid      = (const int*)d_in[2];
    const float* cur_means = (const float*)d_in[3];
    const float* cur_bases = (const float*)d_in[4];
    const float* cur_vars  = (const float*)d_in[5];
    const float* old_means = (const float*)d_in[6];
    const float* old_bases = (const float*)d_in[7];
    const float* old_vars  = (const float*)d_in[8];

    unsigned char* ws = (unsigned char*)d_ws;
    float*    gdist  = (float*)(ws + 0);
    unsigned* ominE  = (unsigned*)(ws + 20480);
    bf16*     zbf    = (bf16*) (ws + 22528);
    float*    znorm  = (float*)(ws + 808960);
    float*    munorm = (float*)(ws + 811008);
    float*    m_c    = (float*)(ws + 811520);
    bf16*     basesT = (bf16*) (ws + 867840);
    bf16*     G      = (bf16*) (ws + 22494720);

    prep_fused<<<dim3(128 + C_TOT), dim3(256), 0, stream>>>(
        features, cur_means, old_means, cur_bases, old_bases,
        zbf, znorm, munorm, m_c, basesT, G, ominE);
    main_dist<<<dim3(896), dim3(256), 0, stream>>>(zbf, basesT, G, m_c,
                                                   cur_vars, old_vars,
                                                   cur_means, old_means,
                                                   znorm, munorm,
                                                   gdist, ominE);
    finalize<<<dim3(1), dim3(512), 0, stream>>>(gdist, ominE, labels, ncid,
                                                (float*)d_out);
}

// Round 9
// 156.494 us; speedup vs baseline: 1.0344x; 1.0344x over previous
//
#include <hip/hip_runtime.h>
#include <hip/hip_bf16.h>
#include <math.h>
#include <stdint.h>

#define B_N   512
#define D_N   768
#define R_N   128
#define C_NEW 10
#define C_OLD 100
#define C_TOT 110
#define MARGIN_F    5.0f
#define VAR_FLOOR_F 1e-4f
#define BIG_F       1e6f

typedef __bf16 bf16;
typedef __bf16 bf16x4 __attribute__((ext_vector_type(4)));
typedef __bf16 bf16x8 __attribute__((ext_vector_type(8)));
typedef float  f32x4  __attribute__((ext_vector_type(4)));

__device__ __forceinline__ float cleanf(float v) { return isfinite(v) ? v : 0.0f; }

// order-preserving float->uint encode (monotone, handles negatives)
__device__ __forceinline__ unsigned encf(float f) {
    unsigned u = __float_as_uint(f);
    return (u & 0x80000000u) ? ~u : (u | 0x80000000u);
}
__device__ __forceinline__ float decf(unsigned u) {
    return (u & 0x80000000u) ? __uint_as_float(u & 0x7fffffffu) : __uint_as_float(~u);
}

// global->LDS direct DMA, 16B per lane; LDS dst is wave-uniform base + lane*16
#define GL16(gp, lp)                                                            \
    __builtin_amdgcn_global_load_lds(                                           \
        (const __attribute__((address_space(1))) unsigned int*)(gp),            \
        (__attribute__((address_space(3))) unsigned int*)(lp), 16, 0, 0)

// Swizzled element offset within a row of 768: granule g (8 elems) of each
// 64-elem chunk is stored at g ^ (row & 7). Applied at WRITE time in prep;
// read side (MFMA frags / zdot) applies the same XOR. LDS stays linear so
// global_load_lds works (both-sides-or-neither rule).
__device__ __forceinline__ int swz_elem(int D, int row) {
    int k0 = D & ~63;
    int g  = (D >> 3) & 7;
    return k0 + (((g ^ (row & 7))) << 3) + (D & 7);
}

// ---------------------------------------------------------------------------
// prep_all: grid 898 x 256.  [R7 structure — parallel paths; the f32 bases
// are read by BOTH gram and transpose blocks (~84 MB logical) but the 42 MB
// array is L3-resident so the second scan is absorbed; fusing them (R8)
// serialized the transpose into gram's critical path and LOST 5 µs.]
//  [0,128):   z-blocks — clean z -> swizzled bf16 zbf + znorm[b]; blk 0 inits ominE.
//  [128,238): gram blocks — G[c] = B_c^T B_c (bf16) from f32 bases via per-chunk
//             LDS transpose; also m_c[c][r] = sum_d mu_d B[d][r] and munorm[c].
//  [238,898): transpose blocks — swizzled basesT[c][r][d] from bases[c][d][r].
// ---------------------------------------------------------------------------
__global__ __launch_bounds__(256, 2)
void prep_all(const float* __restrict__ z,
              const float* __restrict__ cur_means, const float* __restrict__ old_means,
              const float* __restrict__ cur_bases, const float* __restrict__ old_bases,
              bf16* __restrict__ zbf, float* __restrict__ znorm,
              float* __restrict__ munorm, float* __restrict__ m_c,
              bf16* __restrict__ basesT, bf16* __restrict__ G,
              unsigned* __restrict__ ominE)
{
    const int bid = blockIdx.x, t = threadIdx.x;
    __shared__ __align__(16) unsigned char lds[33280];
    const int wave = t >> 6, lane = t & 63;

    if (bid < 128) {
        // ---------------- z path ----------------
        if (bid == 0) {
            ominE[t] = 0xFFFFFFFFu;
            ominE[256 + t] = 0xFFFFFFFFu;
        }
        const int b = bid * 4 + wave;
        const float4* src = (const float4*)(z + (size_t)b * D_N);
        bf16* dst = zbf + (size_t)b * D_N;
        float nrm = 0.f;
        #pragma unroll
        for (int i = 0; i < 3; ++i) {
            const int D = (lane + i * 64) * 4;      // element index in row
            float4 v = src[lane + i * 64];
            v.x = cleanf(v.x); v.y = cleanf(v.y); v.z = cleanf(v.z); v.w = cleanf(v.w);
            nrm += v.x * v.x + v.y * v.y + v.z * v.z + v.w * v.w;
            bf16x4 w;
            w[0] = (bf16)v.x; w[1] = (bf16)v.y; w[2] = (bf16)v.z; w[3] = (bf16)v.w;
            *(bf16x4*)(dst + swz_elem(D, b)) = w;
        }
        #pragma unroll
        for (int off = 32; off >= 1; off >>= 1) nrm += __shfl_xor(nrm, off, 64);
        if (lane == 0) znorm[b] = nrm;
        return;
    }

    if (bid < 128 + C_TOT) {
        // ---------------- gram + m_c + munorm path ----------------
        const int c = bid - 128;
        const float* Bc = (c < C_NEW) ? cur_bases + (size_t)c * D_N * R_N
                                      : old_bases + (size_t)(c - C_NEW) * D_N * R_N;
        const float* mu = (c < C_NEW) ? cur_means + (size_t)c * D_N
                                      : old_means + (size_t)(c - C_NEW) * D_N;
        bf16*  sT   = (bf16*)lds;                     // [128][72] padded
        float* sMuF = (float*)(lds + 18432);          // 64 f32
        float* sRed = (float*)(lds + 18432 + 256);    // 256 f32
        const int quad = lane >> 4, l15 = lane & 15;
        const int wrg = (wave >> 1) * 64, wsg = (wave & 1) * 64;
        const int rg = t & 31, dgq = t >> 5;

        f32x4 acc[4][4];
        #pragma unroll
        for (int i = 0; i < 4; ++i)
            #pragma unroll
            for (int j = 0; j < 4; ++j) acc[i][j] = (f32x4)0.0f;
        float mAcc = 0.f, muN = 0.f;

        float4 pf[8];
        #pragma unroll
        for (int i = 0; i < 2; ++i) {
            const int dg = i * 8 + dgq;
            const float* src = Bc + (size_t)(dg * 4) * R_N + rg * 4;
            #pragma unroll
            for (int m = 0; m < 4; ++m) pf[i * 4 + m] = *(const float4*)(src + m * R_N);
        }

        for (int kc = 0; kc < 12; ++kc) {
            const int k0 = kc * 64;
            __syncthreads();
            #pragma unroll
            for (int i = 0; i < 2; ++i) {
                const int dg = i * 8 + dgq;
                #pragma unroll
                for (int j = 0; j < 4; ++j) {
                    const int R = rg * 4 + j;
                    bf16x4 w;
                    w[0] = (bf16)pf[i * 4 + 0][j];
                    w[1] = (bf16)pf[i * 4 + 1][j];
                    w[2] = (bf16)pf[i * 4 + 2][j];
                    w[3] = (bf16)pf[i * 4 + 3][j];
                    *(bf16x4*)(sT + R * 72 + dg * 4) = w;
                }
            }
            if (t < 64) {
                float mv = mu[k0 + t];
                sMuF[t] = mv;
                muN += mv * mv;
            }
            if (kc < 11) {
                #pragma unroll
                for (int i = 0; i < 2; ++i) {
                    const int dg = i * 8 + dgq;
                    const float* src = Bc + (size_t)((kc + 1) * 64 + dg * 4) * R_N + rg * 4;
                    #pragma unroll
                    for (int m = 0; m < 4; ++m) pf[i * 4 + m] = *(const float4*)(src + m * R_N);
                }
            }
            __syncthreads();
            #pragma unroll
            for (int kk = 0; kk < 64; kk += 32) {
                bf16x8 af[4], bg[4];
                #pragma unroll
                for (int i = 0; i < 4; ++i) af[i] = *(const bf16x8*)(sT + (wrg + 16 * i + l15) * 72 + kk + quad * 8);
                #pragma unroll
                for (int j = 0; j < 4; ++j) bg[j] = *(const bf16x8*)(sT + (wsg + 16 * j + l15) * 72 + kk + quad * 8);
                #pragma unroll
                for (int i = 0; i < 4; ++i)
                    #pragma unroll
                    for (int j = 0; j < 4; ++j)
                        acc[i][j] = __builtin_amdgcn_mfma_f32_16x16x32_bf16(af[i], bg[j], acc[i][j], 0, 0, 0);
            }
            // m_c strip-dot: row r = t>>1, half h = t&1 over 32 k each
            {
                const int rr = t >> 1, hf = t & 1;
                const bf16* tr = sT + rr * 72 + hf * 32;
                const float* mf = sMuF + hf * 32;
                #pragma unroll
                for (int m = 0; m < 4; ++m) {
                    bf16x8 v = *(const bf16x8*)(tr + m * 8);
                    #pragma unroll
                    for (int e = 0; e < 8; ++e) mAcc += (float)v[e] * mf[m * 8 + e];
                }
            }
        }
        #pragma unroll
        for (int i = 0; i < 4; ++i)
            #pragma unroll
            for (int j = 0; j < 4; ++j)
                #pragma unroll
                for (int reg = 0; reg < 4; ++reg) {
                    int r = wrg + 16 * i + quad * 4 + reg;
                    int s = wsg + 16 * j + l15;
                    G[(size_t)c * 16384 + (size_t)r * 128 + s] = (bf16)acc[i][j][reg];
                }
        sRed[t] = mAcc;
        __syncthreads();
        if (t < 128) m_c[c * R_N + t] = sRed[2 * t] + sRed[2 * t + 1];
        if (t < 64) {
            #pragma unroll
            for (int off = 32; off >= 1; off >>= 1) muN += __shfl_xor(muN, off, 64);
            if (lane == 0) munorm[c] = muN;
        }
        return;
    }

    // ---------------- transpose path (swizzled output) ----------------
    const int tb = bid - (128 + C_TOT);
    const int dt = tb % 6, c = tb / 6;
    const float* Bc = (c < C_NEW) ? cur_bases + (size_t)c * D_N * R_N
                                  : old_bases + (size_t)(c - C_NEW) * D_N * R_N;
    bf16 (*T)[128] = (bf16(*)[128])lds;
    const int d0 = dt * 128;
    const int rg  = t & 31;
    const int dgb = t >> 5;

    #pragma unroll
    for (int i = 0; i < 4; ++i) {
        const int dg = i * 8 + dgb;
        const float* src = Bc + (size_t)(d0 + dg * 4) * R_N + rg * 4;
        float4 v0 = *(const float4*)(src);
        float4 v1 = *(const float4*)(src + R_N);
        float4 v2 = *(const float4*)(src + 2 * R_N);
        float4 v3 = *(const float4*)(src + 3 * R_N);
        const float* f0 = (const float*)&v0;
        const float* f1 = (const float*)&v1;
        const float* f2 = (const float*)&v2;
        const float* f3 = (const float*)&v3;
        #pragma unroll
        for (int j = 0; j < 4; ++j) {
            const int R = rg * 4 + j;
            const int pc = dg ^ (R & 31);          // LDS tile anti-conflict swizzle
            bf16x4 w;
            w[0] = (bf16)f0[j]; w[1] = (bf16)f1[j]; w[2] = (bf16)f2[j]; w[3] = (bf16)f3[j];
            *(bf16x4*)(&T[R][pc * 4]) = w;
        }
    }
    __syncthreads();

    #pragma unroll
    for (int it = 0; it < 16; ++it) {
        const int q = it * 256 + t;
        const int r = q >> 5, u = q & 31;
        const int pc = u ^ (r & 31);
        ushort4 w = *(const ushort4*)(&T[r][pc * 4]);
        const int D = d0 + u * 4;                  // element col in full row
        *(ushort4*)(basesT + (size_t)c * R_N * D_N + (size_t)r * D_N + swz_elem(D, r)) = w;
    }
}

// ---------------------------------------------------------------------------
// main_dist: grid 896 x 256, 4 blocks/CU. Decode: c = (fid&7) + 8*((fid%112)>>3),
// mt = fid/112 -> 8 mt-blocks of a class share one XCD's L2 (basesT/G reuse).
// K-loop (12 chunks): LDS staging via global_load_lds width-16 DMA from the
// PRE-SWIZZLED zbf/basesT (linear LDS dest, XOR applied at frag-read time).
// acc1 = z x B; epilogue: coeff = acc1 - m_c -> sC; par/cn; GEMM2 H = coeff x G
// (G straight from L2); qsum; dist with nd2 = znorm - 2 zdot + munorm.
// ---------------------------------------------------------------------------
#define PADC 136
#define SM_A    0                       // 64 x 64 bf16 linear = 8192
#define SM_B    8192                    // 128 x 64 bf16 linear = 16384 -> 24576
#define SM_C    0                       // 64x136 bf16 = 17408 (overlay sA/sB)
#define SM_MU   24576                   // 768 bf16 = 1536 -> 26112
#define SM_M    26112                   // 128 f32 = 512 -> 26624
#define SM_INV  26624                   // 512 -> 27136
#define SM_Q    27136                   // 256 -> 27392
#define SM_PAR  27392                   // 256 -> 27648
#define SM_CN   27648                   // 256 -> 27904
#define SM_ZD   27904                   // 256 -> 28160
#define SM_T2   28160                   // 2048 -> 30208
#define SM_SZ   30208                   // 4+ blocks/CU

__global__ __launch_bounds__(256, 4)
void main_dist(const bf16* __restrict__ zbf, const bf16* __restrict__ basesT,
               const bf16* __restrict__ G, const float* __restrict__ m_c,
               const float* __restrict__ cur_vars, const float* __restrict__ old_vars,
               const float* __restrict__ cur_means, const float* __restrict__ old_means,
               const float* __restrict__ znorm, const float* __restrict__ munorm,
               float* __restrict__ gdist, unsigned* __restrict__ ominE)
{
    const int fid = blockIdx.x;
    const int x = fid & 7;
    const int y = (fid % 112) >> 3;
    const int mt = fid / 112;
    const int c = x + 8 * y;
    if (c >= C_TOT) return;

    __shared__ __align__(16) unsigned char smem[SM_SZ];
    unsigned char* sAb = smem + SM_A;
    unsigned char* sBb = smem + SM_B;
    bf16*  sC   = (bf16*)(smem + SM_C);
    bf16*  sMuB = (bf16*)(smem + SM_MU);
    float* sM   = (float*)(smem + SM_M);
    float* sInv = (float*)(smem + SM_INV);
    float* sQ   = (float*)(smem + SM_Q);
    float* sPar = (float*)(smem + SM_PAR);
    float* sCn  = (float*)(smem + SM_CN);
    float* sZd  = (float*)(smem + SM_ZD);
    float* sT2  = (float*)(smem + SM_T2);

    const int tid = threadIdx.x, wave = tid >> 6, lane = tid & 63;
    const int quad = lane >> 4, l15 = lane & 15;
    const int wr  = (wave >> 1) * 32;      // row half of 64
    const int wcc = (wave & 1) * 64;       // col half of 128

    const int b0 = mt * 64;
    const float* vars = (c < C_NEW) ? cur_vars + (size_t)c * (R_N + 1)
                                    : old_vars + (size_t)(c - C_NEW) * (R_N + 1);
    const float* mu = (c < C_NEW) ? cur_means + (size_t)c * D_N
                                  : old_means + (size_t)(c - C_NEW) * D_N;

    if (tid < 128) {
        sM[tid]   = m_c[c * R_N + tid];
        sInv[tid] = 1.0f / fmaxf(vars[tid], VAR_FLOOR_F);
    }
    if (tid < 64) sQ[tid] = 0.0f;
    for (int i = tid; i < D_N; i += 256) sMuB[i] = (bf16)mu[i];

    f32x4 acc1[2][4];
    #pragma unroll
    for (int i = 0; i < 2; ++i)
        #pragma unroll
        for (int j = 0; j < 4; ++j) acc1[i][j] = (f32x4)0.0f;
    float zd = 0.f;
    const int zrow = tid >> 2, zpart = tid & 3;   // 4 threads per batch row

    // per-thread DMA source offset: row = wave*8 + (lane>>3) (+32 per extra call),
    // 16B granule (lane&7) within the 128B chunk-row
    const char* BbB = (const char*)basesT + (size_t)c * (R_N * D_N * 2);
    const char* AzB = (const char*)zbf + (size_t)b0 * (D_N * 2);
    const int offRC = (wave * 8 + (lane >> 3)) * (D_N * 2) + (lane & 7) * 16;
    char* ldsB = (char*)sBb + wave * 1024;
    char* ldsA = (char*)sAb + wave * 1024;

    for (int kc = 0; kc < 12; ++kc) {
        const int kb = kc * 128;               // byte offset within a 1536B row
        const int k0 = kc * 64;                // element offset
        __syncthreads();                       // previous chunk's readers done
        #pragma unroll
        for (int p = 0; p < 4; ++p)
            GL16(BbB + offRC + p * (32 * D_N * 2) + kb, ldsB + p * 4096);
        #pragma unroll
        for (int q = 0; q < 2; ++q)
            GL16(AzB + offRC + q * (32 * D_N * 2) + kb, ldsA + q * 4096);
        __syncthreads();                       // vmcnt(0) drain inserted by compiler
        #pragma unroll
        for (int kk = 0; kk < 64; kk += 32) {
            const int gbase = kk >> 3;
            bf16x8 af[2], bg[4];
            #pragma unroll
            for (int i = 0; i < 2; ++i) {
                const int rowA = wr + 16 * i + l15;
                af[i] = *(const bf16x8*)(sAb + rowA * 128 + (((gbase + quad) ^ (rowA & 7)) << 4));
            }
            #pragma unroll
            for (int j = 0; j < 4; ++j) {
                const int rowB = wcc + 16 * j + l15;
                bg[j] = *(const bf16x8*)(sBb + rowB * 128 + (((gbase + quad) ^ (rowB & 7)) << 4));
            }
            #pragma unroll
            for (int i = 0; i < 2; ++i)
                #pragma unroll
                for (int j = 0; j < 4; ++j)
                    acc1[i][j] = __builtin_amdgcn_mfma_f32_16x16x32_bf16(af[i], bg[j], acc1[i][j], 0, 0, 0);
        }
        // zdot co-issue: z[row] . mu over this chunk (2 granules per thread)
        #pragma unroll
        for (int gg = 0; gg < 2; ++gg) {
            const int g = zpart * 2 + gg;
            bf16x8 a = *(const bf16x8*)(sAb + zrow * 128 + ((g ^ (zrow & 7)) << 4));
            bf16x8 b = *(const bf16x8*)(sMuB + k0 + g * 8);
            #pragma unroll
            for (int e = 0; e < 8; ++e) zd += (float)a[e] * (float)b[e];
        }
    }

    // zdot reduce: 4 consecutive lanes share a row
    zd += __shfl_xor(zd, 1, 64);
    zd += __shfl_xor(zd, 2, 64);
    if ((tid & 3) == 0) sZd[zrow] = zd;
    __syncthreads();   // all waves done reading sA/sB; sZd complete

    // coeff = acc1 - m_c -> sC (overlays sA/sB region)
    #pragma unroll
    for (int j = 0; j < 4; ++j) {
        float mcv = sM[wcc + 16 * j + l15];
        #pragma unroll
        for (int i = 0; i < 2; ++i)
            #pragma unroll
            for (int reg = 0; reg < 4; ++reg)
                sC[(wr + 16 * i + quad * 4 + reg) * PADC + wcc + 16 * j + l15] =
                    (bf16)(acc1[i][j][reg] - mcv);
    }
    __syncthreads();

    // par / cnorm per row (64 rows, 4 threads/row over 32 cols each)
    {
        int row = tid >> 2, qtr = tid & 3;
        float par = 0.f, cn = 0.f;
        #pragma unroll
        for (int m = 0; m < 4; ++m) {
            bf16x8 v = *(const bf16x8*)(sC + row * PADC + qtr * 32 + m * 8);
            #pragma unroll
            for (int e = 0; e < 8; ++e) {
                float f = (float)v[e];
                int col = qtr * 32 + m * 8 + e;
                cn  += f * f;
                par += f * f * sInv[col];
            }
        }
        sT2[tid] = par;
        sT2[256 + tid] = cn;
    }
    __syncthreads();
    if (tid < 64) {
        sPar[tid] = sT2[tid * 4] + sT2[tid * 4 + 1] + sT2[tid * 4 + 2] + sT2[tid * 4 + 3];
        sCn[tid]  = sT2[256 + tid * 4] + sT2[256 + tid * 4 + 1]
                  + sT2[256 + tid * 4 + 2] + sT2[256 + tid * 4 + 3];
    }

    // GEMM2: H = coeff x G; G-fragments straight from global (L2-hot)
    const bf16* Gc = G + (size_t)c * 16384;
    f32x4 acc2[2][4];
    #pragma unroll
    for (int i = 0; i < 2; ++i)
        #pragma unroll
        for (int j = 0; j < 4; ++j) acc2[i][j] = (f32x4)0.0f;
    #pragma unroll
    for (int kc4 = 0; kc4 < 4; ++kc4) {
        const int kb = kc4 * 32;
        bf16x8 af[2], bg[4];
        #pragma unroll
        for (int i = 0; i < 2; ++i) af[i] = *(const bf16x8*)(sC + (wr + 16 * i + l15) * PADC + kb + quad * 8);
        #pragma unroll
        for (int j = 0; j < 4; ++j) bg[j] = *(const bf16x8*)(Gc + (size_t)(wcc + 16 * j + l15) * 128 + kb + quad * 8);
        #pragma unroll
        for (int i = 0; i < 2; ++i)
            #pragma unroll
            for (int j = 0; j < 4; ++j)
                acc2[i][j] = __builtin_amdgcn_mfma_f32_16x16x32_bf16(af[i], bg[j], acc2[i][j], 0, 0, 0);
    }

    // qsum[row] = sum_s H[row][s] * coeff[row][s]  (coeff from sC)
    #pragma unroll
    for (int i = 0; i < 2; ++i)
        #pragma unroll
        for (int reg = 0; reg < 4; ++reg) {
            const int row = wr + 16 * i + quad * 4 + reg;
            float qp = 0.f;
            #pragma unroll
            for (int j = 0; j < 4; ++j)
                qp += acc2[i][j][reg] * (float)sC[row * PADC + wcc + 16 * j + l15];
            qp += __shfl_xor(qp, 1, 64);
            qp += __shfl_xor(qp, 2, 64);
            qp += __shfl_xor(qp, 4, 64);
            qp += __shfl_xor(qp, 8, 64);
            if (l15 == 0) atomicAdd(&sQ[row], qp);
        }
    __syncthreads();

    // final dist per row
    if (tid < 64) {
        int b = b0 + tid;
        float nd2 = znorm[b] - 2.0f * sZd[tid] + munorm[c];
        float res = fmaxf(vars[R_N], VAR_FLOOR_F);
        float dist = (sPar[tid] + (nd2 - 2.0f * sCn[tid] + sQ[tid]) / res) / (float)D_N;
        if (!isfinite(dist)) dist = BIG_F;
        if (c < C_NEW) {
            gdist[(size_t)b * C_NEW + c] = dist;
        } else {
            atomicMin(ominE + b, encf(dist));
        }
    }
}

// ---------------------------------------------------------------------------
// finalize: single block, 512 threads (one per batch row).
// ---------------------------------------------------------------------------
__global__ __launch_bounds__(512)
void finalize(const float* __restrict__ gdist, const unsigned* __restrict__ ominE,
              const int* __restrict__ labels, const int* __restrict__ ncid,
              float* __restrict__ out)
{
    __shared__ float acc[C_NEW * 4];
    __shared__ int sNcid[C_NEW];
    const int t = threadIdx.x;
    if (t < C_NEW * 4) acc[t] = 0.f;
    if (t < C_NEW) sNcid[t] = ncid[t];
    __syncthreads();

    {
        float mn = decf(ominE[t]);
        const int lab = labels[t];
        #pragma unroll
        for (int k = 0; k < C_NEW; ++k) {
            if (lab == sNcid[k]) {
                int col = min(max(sNcid[k], 0), C_NEW - 1);
                float ow = gdist[(size_t)t * C_NEW + col];
                atomicAdd(&acc[k * 4 + 0], 1.0f);
                atomicAdd(&acc[k * 4 + 1], fmaxf(0.0f, MARGIN_F + ow - mn));
                atomicAdd(&acc[k * 4 + 2], ow);
                atomicAdd(&acc[k * 4 + 3], mn);
            }
        }
    }
    __syncthreads();

    if (t == 0) {
        float total = 0.f, own = 0.f, old = 0.f, nv = 0.f;
        #pragma unroll
        for (int k = 0; k < C_NEW; ++k) {
            float cnt = acc[k * 4 + 0];
            float den = fmaxf(cnt, 1.0f);
            if (cnt > 0.f) {
                nv += 1.f;
                total += acc[k * 4 + 1] / den;
                own   += acc[k * 4 + 2] / den;
                old   += acc[k * 4 + 3] / den;
            }
        }
        float nvd = fmaxf(nv, 1.0f);
        out[0] = total / nvd;
        out[1] = own / nvd;
        out[2] = old / nvd;
    }
}

// ---------------------------------------------------------------------------
// workspace layout (bytes):
//   gdist  @ 0        : 20480    (512 x 10 f32, new classes only)
//   ominE  @ 20480    : 2048     (512 encoded old-min; init by prep blk 0)
//   zbf    @ 22528    : 786432   (swizzled bf16 z)
//   znorm  @ 808960   : 2048
//   munorm @ 811008   : 512
//   m_c    @ 811520   : 56320
//   basesT @ 867840   : 21626880 (swizzled)
//   G      @ 22494720 : 3604480  -> total ~26.1 MB
// ---------------------------------------------------------------------------
extern "C" void kernel_launch(void* const* d_in, const int* in_sizes, int n_in,
                              void* d_out, int out_size, void* d_ws, size_t ws_size,
                              hipStream_t stream)
{
    const float* features  = (const float*)d_in[0];
    const int*   labels    = (const int*)d_in[1];
    const int*   ncid      = (const int*)d_in[2];
    const float* cur_means = (const float*)d_in[3];
    const float* cur_bases = (const float*)d_in[4];
    const float* cur_vars  = (const float*)d_in[5];
    const float* old_means = (const float*)d_in[6];
    const float* old_bases = (const float*)d_in[7];
    const float* old_vars  = (const float*)d_in[8];

    unsigned char* ws = (unsigned char*)d_ws;
    float*    gdist  = (float*)(ws + 0);
    unsigned* ominE  = (unsigned*)(ws + 20480);
    bf16*     zbf    = (bf16*) (ws + 22528);
    float*    znorm  = (float*)(ws + 808960);
    float*    munorm = (float*)(ws + 811008);
    float*    m_c    = (float*)(ws + 811520);
    bf16*     basesT = (bf16*) (ws + 867840);
    bf16*     G      = (bf16*) (ws + 22494720);

    prep_all<<<dim3(128 + C_TOT + 6 * C_TOT), dim3(256), 0, stream>>>(
        features, cur_means, old_means, cur_bases, old_bases,
        zbf, znorm, munorm, m_c, basesT, G, ominE);
    main_dist<<<dim3(896), dim3(256), 0, stream>>>(zbf, basesT, G, m_c,
                                                   cur_vars, old_vars,
                                                   cur_means, old_means,
                                                   znorm, munorm,
                                                   gdist, ominE);
    finalize<<<dim3(1), dim3(512), 0, stream>>>(gdist, ominE, labels, ncid,
                                                (float*)d_out);
}